// Round 3
// baseline (158.972 us; speedup 1.0000x reference)
//
#include <hip/hip_runtime.h>
#include <hip/hip_bf16.h>
#include <cstdint>
#include <cstddef>

#define NROWS 8192
#define KDIM  2048
#define ODIM  1000
#define NSUB  8
#define OPAD  1024   // padded output dim for Wt

#define BM 128
#define BN 128
#define BK 32        // 4-slot pipeline; BK=32 => conflict-free linear LDS layout
#define NSTEP (KDIM / BK)   // 64

typedef __attribute__((ext_vector_type(4))) float f32x4;
typedef __attribute__((ext_vector_type(8))) short short8v;
typedef __attribute__((ext_vector_type(4))) unsigned short u16x4;
typedef __attribute__((ext_vector_type(4))) int int4v;

__device__ __forceinline__ unsigned short f2bf(float f){
  unsigned u = __builtin_bit_cast(unsigned, f);
  unsigned r = (u + 0x7FFFu + ((u >> 16) & 1u)) >> 16;  // RNE
  return (unsigned short)r;
}

__device__ __forceinline__ void gload16(const void* g, void* l){
  __builtin_amdgcn_global_load_lds(
      (const __attribute__((address_space(1))) void*)g,
      (__attribute__((address_space(3))) void*)l, 16, 0, 0);
}

// ---------------- K1: build perm/counts/offsets in ONE kernel ----------------
__global__ __launch_bounds__(256) void build_perm(const int* __restrict__ sid,
                                                  int* __restrict__ counts,
                                                  int* __restrict__ offsets,
                                                  int* __restrict__ perm){
  int s = blockIdx.x;
  __shared__ int shs[NROWS];          // 32KB cached sid
  __shared__ int red_lt[4], red_eq[4], wsum[4];
  __shared__ int sh_base;

  int t = threadIdx.x, lane = t & 63, wv = t >> 6;

  int c_lt = 0, c_eq = 0;
  const int4v* sv = (const int4v*)sid;
  #pragma unroll
  for (int i = 0; i < NROWS / 4 / 256; i++){
    int idx = i * 256 + t;
    int4v v = sv[idx];
    *(int4v*)&shs[idx * 4] = v;
    #pragma unroll
    for (int e = 0; e < 4; e++){ c_lt += (v[e] < s); c_eq += (v[e] == s); }
  }
  #pragma unroll
  for (int d = 32; d >= 1; d >>= 1){
    c_lt += __shfl_xor(c_lt, d);
    c_eq += __shfl_xor(c_eq, d);
  }
  if (lane == 0){ red_lt[wv] = c_lt; red_eq[wv] = c_eq; }
  __syncthreads();
  if (t == 0){
    int lt = red_lt[0] + red_lt[1] + red_lt[2] + red_lt[3];
    int eq = red_eq[0] + red_eq[1] + red_eq[2] + red_eq[3];
    offsets[s] = lt;
    counts[s]  = eq;
    sh_base = lt;
  }
  __syncthreads();
  int base = sh_base;

  for (int c0 = 0; c0 < NROWS; c0 += 256){
    int v = shs[c0 + t];
    bool eq = (v == s);
    unsigned long long m = __ballot(eq);
    int rk = __popcll(m & ((1ull << lane) - 1ull));
    int wc = __popcll(m);
    if (lane == 0) wsum[wv] = wc;
    __syncthreads();
    int woff = 0;
    #pragma unroll
    for (int w = 0; w < 4; w++) if (w < wv) woff += wsum[w];
    int tot = wsum[0] + wsum[1] + wsum[2] + wsum[3];
    if (eq) perm[base + woff + rk] = c0 + t;
    base += tot;
    __syncthreads();
  }
}

// ---------------- K2: fused gather(x->xs bf16 sorted) + transpose(W->Wt bf16) ----------------
__global__ __launch_bounds__(256) void prep_fused(const float* __restrict__ x,
                                                  const int* __restrict__ perm,
                                                  unsigned short* __restrict__ xs,
                                                  const float* __restrict__ W,
                                                  unsigned short* __restrict__ Wt){
  __shared__ float tile[64][65];
  int b = blockIdx.x;
  int t = threadIdx.x;
  if (b < NROWS){
    int orow = perm[b];
    const f32x4* src = (const f32x4*)(x + (size_t)orow * KDIM);
    u16x4* dst = (u16x4*)(xs + (size_t)b * KDIM);
    #pragma unroll
    for (int c = 0; c < 2; c++){
      f32x4 v = src[c * 256 + t];
      u16x4 o;
      o[0] = f2bf(v[0]); o[1] = f2bf(v[1]); o[2] = f2bf(v[2]); o[3] = f2bf(v[3]);
      dst[c * 256 + t] = o;
    }
    return;
  }
  int b2 = b - NROWS;
  int s  = b2 >> 9;
  int kt = (b2 >> 4) & 31;
  int ot = b2 & 15;
  int k0 = kt * 64, o0 = ot * 64;
  int ol = t & 63, kr = t >> 6;
  const float* src = W + ((size_t)s * KDIM + k0) * ODIM + o0;
  bool oval = (o0 + ol) < ODIM;
  #pragma unroll
  for (int it = 0; it < 16; it++){
    int k = kr * 16 + it;
    tile[k][ol] = oval ? src[(size_t)k * ODIM + ol] : 0.f;
  }
  __syncthreads();
  int kp = t & 31, orow = t >> 5;
  unsigned short* dst = Wt + ((size_t)(s * OPAD + o0)) * KDIM + k0;
  #pragma unroll
  for (int it = 0; it < 8; it++){
    int o = orow + it * 8;
    bool valid = (o0 + o) < ODIM;        // pad rows -> zeros
    unsigned lo = valid ? (unsigned)f2bf(tile[kp * 2][o])     : 0u;
    unsigned hi = valid ? (unsigned)f2bf(tile[kp * 2 + 1][o]) : 0u;
    *(unsigned*)(dst + (size_t)o * KDIM + kp * 2) = lo | (hi << 16);
  }
}

// ---------------- K3: grouped bf16 MFMA GEMM, 128x128, BK=32, 4-slot counted-vmcnt pipeline ----------------
__global__ __launch_bounds__(256) void gemm_bf16(
    const unsigned short* __restrict__ xs,   // [8192][2048] bf16 (sorted)
    const unsigned short* __restrict__ Wt,   // [8][1024][2048] bf16
    const int* __restrict__ counts,
    const int* __restrict__ offsets,
    const int* __restrict__ perm,
    const float* __restrict__ bias,          // [8][1000]
    float* __restrict__ out)                 // [8192][1000]
{
  int s  = blockIdx.z;
  int mt = blockIdx.y;
  int nt = blockIdx.x;
  int cnt = counts[s];
  int loc0 = mt * BM;
  if (loc0 >= cnt) return;
  int row0 = offsets[s] + loc0;
  int cnt_loc = cnt - loc0;

  __shared__ unsigned short lA[4][BM * BK];  // 4 x 8KB
  __shared__ unsigned short lB[4][BN * BK];  // 4 x 8KB
  __shared__ int permL[BM];

  int t = threadIdx.x;
  int lane = t & 63;
  int wave = t >> 6;

  int rp = -1;
  if (t < BM && t < cnt_loc) rp = perm[row0 + t];   // vmem load, drained in prologue

  int wm = (wave >> 1) << 6;   // 2x2 waves, wave-tile 64x64
  int wn = (wave & 1) << 6;
  int frow = lane & 15, fk = lane >> 4;

  // staging: each wave stages 2 contiguous 1KB chunks of A and of B per slot.
  // chunk c covers rows c*16..c*16+15 (32 bf16 per row, row stride 64B) — fully
  // linear both sides => no swizzle, no extra bank conflicts.
  int c0 = wave * 2, c1 = c0 + 1;
  int r0 = c0 * 16 + (lane >> 2);
  int r1 = c1 * 16 + (lane >> 2);
  int ke = (lane & 3) * 8;
  int raA0 = row0 + r0; if (raA0 > NROWS - 1) raA0 = NROWS - 1;
  int raA1 = row0 + r1; if (raA1 > NROWS - 1) raA1 = NROWS - 1;
  size_t gA0 = (size_t)raA0 * KDIM + ke;
  size_t gA1 = (size_t)raA1 * KDIM + ke;
  size_t gB0 = ((size_t)(s * OPAD + nt * BN + r0)) * KDIM + ke;
  size_t gB1 = ((size_t)(s * OPAD + nt * BN + r1)) * KDIM + ke;
  unsigned lo0 = (unsigned)(c0 * 512 + lane * 8);
  unsigned lo1 = (unsigned)(c1 * 512 + lane * 8);

  f32x4 acc[4][4];
  #pragma unroll
  for (int i = 0; i < 4; i++)
    #pragma unroll
    for (int j = 0; j < 4; j++)
      #pragma unroll
      for (int e = 0; e < 4; e++) acc[i][j][e] = 0.f;

#define STAGE(slot, koff) do { \
    gload16(xs + gA0 + (koff), (void*)(&lA[slot][lo0])); \
    gload16(xs + gA1 + (koff), (void*)(&lA[slot][lo1])); \
    gload16(Wt + gB0 + (koff), (void*)(&lB[slot][lo0])); \
    gload16(Wt + gB1 + (koff), (void*)(&lB[slot][lo1])); \
  } while (0)

#define COMPUTE(slot) do { \
    short8v a[4], b[4]; \
    _Pragma("unroll") \
    for (int mi = 0; mi < 4; mi++) \
      a[mi] = *(const short8v*)&lA[slot][((wm + (mi << 4) + frow) << 5) + (fk << 3)]; \
    _Pragma("unroll") \
    for (int ni = 0; ni < 4; ni++) \
      b[ni] = *(const short8v*)&lB[slot][((wn + (ni << 4) + frow) << 5) + (fk << 3)]; \
    _Pragma("unroll") \
    for (int mi = 0; mi < 4; mi++) \
      _Pragma("unroll") \
      for (int ni = 0; ni < 4; ni++) \
        acc[mi][ni] = __builtin_amdgcn_mfma_f32_16x16x32_bf16(a[mi], b[ni], acc[mi][ni], 0, 0, 0); \
  } while (0)

// counted-vmcnt barrier: waits only the OLDEST 4 loads (current slot),
// leaving the 4 just-issued prefetch loads in flight ACROSS the barrier.
#define WB4() do { \
    asm volatile("s_waitcnt vmcnt(4)" ::: "memory"); \
    __builtin_amdgcn_sched_barrier(0); \
    __builtin_amdgcn_s_barrier(); \
    __builtin_amdgcn_sched_barrier(0); \
  } while (0)

  // prologue: 2 slots in flight
  STAGE(0, 0);
  STAGE(1, BK);
  if (t < BM) permL[t] = rp;
  asm volatile("s_waitcnt vmcnt(4) lgkmcnt(0)" ::: "memory");
  __builtin_amdgcn_sched_barrier(0);
  __builtin_amdgcn_s_barrier();
  __builtin_amdgcn_sched_barrier(0);

  // steady state: steps 0..59 (15 iters x 4 sub-steps, static slot indices)
  for (int it = 0; it < 15; ++it){
    int kb = (it * 4 + 2) * BK;   // element offset of first staged step
    WB4(); STAGE(2, kb);          COMPUTE(0);
    WB4(); STAGE(3, kb + BK);     COMPUTE(1);
    WB4(); STAGE(0, kb + 2 * BK); COMPUTE(2);
    WB4(); STAGE(1, kb + 3 * BK); COMPUTE(3);
  }
  // tail: steps 60..63
  WB4(); STAGE(2, 62 * BK); COMPUTE(0);
  WB4(); STAGE(3, 63 * BK); COMPUTE(1);
  WB4();                    COMPUTE(2);
  asm volatile("s_waitcnt vmcnt(0)" ::: "memory");
  __builtin_amdgcn_sched_barrier(0);
  __builtin_amdgcn_s_barrier();
  __builtin_amdgcn_sched_barrier(0);
  COMPUTE(3);

  // epilogue: C/D layout col=lane&15, row=(lane>>4)*4+reg
  float bvn[4]; int ocol[4];
  #pragma unroll
  for (int ni = 0; ni < 4; ni++){
    int o = (nt << 7) + wn + (ni << 4) + frow;
    ocol[ni] = o;
    bvn[ni] = (o < ODIM) ? bias[s * ODIM + o] : 0.f;
  }
  #pragma unroll
  for (int mi = 0; mi < 4; mi++){
    int rbase = wm + (mi << 4) + (fk << 2);
    #pragma unroll
    for (int jj = 0; jj < 4; jj++){
      int orow = permL[rbase + jj];
      if (orow >= 0){
        #pragma unroll
        for (int ni = 0; ni < 4; ni++){
          if (ocol[ni] < ODIM)
            out[(size_t)orow * ODIM + ocol[ni]] = acc[mi][ni][jj] + bvn[ni];
        }
      }
    }
  }
#undef STAGE
#undef COMPUTE
#undef WB4
}

// ---------------- fallback: naive fp32 (only if ws too small) ----------------
__global__ __launch_bounds__(256) void naive_kernel(const float* __restrict__ x,
                                                    const int* __restrict__ sid,
                                                    const float* __restrict__ W,
                                                    const float* __restrict__ bias,
                                                    float* __restrict__ out){
  __shared__ float xr[KDIM];
  int row = blockIdx.x;
  int s = sid[row];
  for (int i = threadIdx.x; i < KDIM; i += 256) xr[i] = x[(size_t)row * KDIM + i];
  __syncthreads();
  int o = blockIdx.y * 256 + threadIdx.x;
  if (o >= ODIM) return;
  const float* w = W + (size_t)s * KDIM * ODIM + o;
  float acc = bias[s * ODIM + o];
  for (int k = 0; k < KDIM; k++) acc = fmaf(xr[k], w[(size_t)k * ODIM], acc);
  out[(size_t)row * ODIM + o] = acc;
}

extern "C" void kernel_launch(void* const* d_in, const int* in_sizes, int n_in,
                              void* d_out, int out_size, void* d_ws, size_t ws_size,
                              hipStream_t stream) {
  const float* x    = (const float*)d_in[0];
  const int*   sid  = (const int*)d_in[1];
  const float* W    = (const float*)d_in[2];
  const float* bias = (const float*)d_in[3];
  float* out = (float*)d_out;

  const size_t XS_BYTES = (size_t)NROWS * KDIM * 2;
  const size_t WT_BYTES = (size_t)NSUB * OPAD * KDIM * 2;
  const size_t need = 64 + (size_t)NROWS * 4 + XS_BYTES + WT_BYTES;

  if (ws_size < need){
    naive_kernel<<<dim3(NROWS, 4), 256, 0, stream>>>(x, sid, W, bias, out);
    return;
  }

  char* w = (char*)d_ws;
  int* counts  = (int*)w;                      // 8 ints
  int* offsets = counts + 8;                   // 8 ints
  int* perm    = (int*)(w + 64);               // 8192 ints
  unsigned short* xs = (unsigned short*)(w + 64 + (size_t)NROWS * 4);
  unsigned short* Wt = xs + (size_t)NROWS * KDIM;

  build_perm <<<NSUB, 256, 0, stream>>>(sid, counts, offsets, perm);
  prep_fused <<<NROWS + 4096, 256, 0, stream>>>(x, perm, xs, W, Wt);
  gemm_bf16  <<<dim3(8, 64, NSUB), 256, 0, stream>>>(xs, Wt, counts, offsets, perm, bias, out);
}

// Round 4
// 121.070 us; speedup vs baseline: 1.3131x; 1.3131x over previous
//
#include <hip/hip_runtime.h>
#include <hip/hip_bf16.h>
#include <cstdint>
#include <cstddef>

#define NROWS 8192
#define KDIM  2048
#define ODIM  1000
#define NSUB  8
#define OPAD  1024   // padded output dim for Wt

#define BM 128
#define BN 128
#define BK 64
#define MT_MAX 10    // covers any multinomial count (<=1280 rows/subject)

typedef __attribute__((ext_vector_type(4))) float f32x4;
typedef __attribute__((ext_vector_type(8))) short short8v;
typedef __attribute__((ext_vector_type(4))) unsigned short u16x4;
typedef __attribute__((ext_vector_type(4))) int int4v;

__device__ __forceinline__ unsigned short f2bf(float f){
  unsigned u = __builtin_bit_cast(unsigned, f);
  unsigned r = (u + 0x7FFFu + ((u >> 16) & 1u)) >> 16;  // RNE
  return (unsigned short)r;
}

__device__ __forceinline__ void gload16(const void* g, void* l){
  __builtin_amdgcn_global_load_lds(
      (const __attribute__((address_space(1))) void*)g,
      (__attribute__((address_space(3))) void*)l, 16, 0, 0);
}

// ---------------- K1: build perm/counts/offsets in ONE kernel ----------------
__global__ __launch_bounds__(256) void build_perm(const int* __restrict__ sid,
                                                  int* __restrict__ counts,
                                                  int* __restrict__ offsets,
                                                  int* __restrict__ perm){
  int s = blockIdx.x;
  __shared__ int shs[NROWS];          // 32KB cached sid
  __shared__ int red_lt[4], red_eq[4], wsum[4];
  __shared__ int sh_base;

  int t = threadIdx.x, lane = t & 63, wv = t >> 6;

  int c_lt = 0, c_eq = 0;
  const int4v* sv = (const int4v*)sid;
  #pragma unroll
  for (int i = 0; i < NROWS / 4 / 256; i++){
    int idx = i * 256 + t;
    int4v v = sv[idx];
    *(int4v*)&shs[idx * 4] = v;
    #pragma unroll
    for (int e = 0; e < 4; e++){ c_lt += (v[e] < s); c_eq += (v[e] == s); }
  }
  #pragma unroll
  for (int d = 32; d >= 1; d >>= 1){
    c_lt += __shfl_xor(c_lt, d);
    c_eq += __shfl_xor(c_eq, d);
  }
  if (lane == 0){ red_lt[wv] = c_lt; red_eq[wv] = c_eq; }
  __syncthreads();
  if (t == 0){
    int lt = red_lt[0] + red_lt[1] + red_lt[2] + red_lt[3];
    int eq = red_eq[0] + red_eq[1] + red_eq[2] + red_eq[3];
    offsets[s] = lt;
    counts[s]  = eq;
    sh_base = lt;
  }
  __syncthreads();
  int base = sh_base;

  for (int c0 = 0; c0 < NROWS; c0 += 256){
    int v = shs[c0 + t];
    bool eq = (v == s);
    unsigned long long m = __ballot(eq);
    int rk = __popcll(m & ((1ull << lane) - 1ull));
    int wc = __popcll(m);
    if (lane == 0) wsum[wv] = wc;
    __syncthreads();
    int woff = 0;
    #pragma unroll
    for (int w = 0; w < 4; w++) if (w < wv) woff += wsum[w];
    int tot = wsum[0] + wsum[1] + wsum[2] + wsum[3];
    if (eq) perm[base + woff + rk] = c0 + t;
    base += tot;
    __syncthreads();
  }
}

// ---------------- K2: fused gather(x->xs bf16 sorted) + transpose(W->Wt bf16) ----------------
__global__ __launch_bounds__(256) void prep_fused(const float* __restrict__ x,
                                                  const int* __restrict__ perm,
                                                  unsigned short* __restrict__ xs,
                                                  const float* __restrict__ W,
                                                  unsigned short* __restrict__ Wt){
  __shared__ float tile[64][65];
  int b = blockIdx.x;
  int t = threadIdx.x;
  if (b < NROWS){
    int orow = perm[b];
    const f32x4* src = (const f32x4*)(x + (size_t)orow * KDIM);
    u16x4* dst = (u16x4*)(xs + (size_t)b * KDIM);
    #pragma unroll
    for (int c = 0; c < 2; c++){
      f32x4 v = src[c * 256 + t];
      u16x4 o;
      o[0] = f2bf(v[0]); o[1] = f2bf(v[1]); o[2] = f2bf(v[2]); o[3] = f2bf(v[3]);
      dst[c * 256 + t] = o;
    }
    return;
  }
  int b2 = b - NROWS;
  int s  = b2 >> 9;
  int kt = (b2 >> 4) & 31;
  int ot = b2 & 15;
  int k0 = kt * 64, o0 = ot * 64;
  int ol = t & 63, kr = t >> 6;
  const float* src = W + ((size_t)s * KDIM + k0) * ODIM + o0;
  bool oval = (o0 + ol) < ODIM;
  #pragma unroll
  for (int it = 0; it < 16; it++){
    int k = kr * 16 + it;
    tile[k][ol] = oval ? src[(size_t)k * ODIM + ol] : 0.f;
  }
  __syncthreads();
  int kp = t & 31, orow = t >> 5;
  unsigned short* dst = Wt + ((size_t)(s * OPAD + o0)) * KDIM + k0;
  #pragma unroll
  for (int it = 0; it < 8; it++){
    int o = orow + it * 8;
    bool valid = (o0 + o) < ODIM;        // pad rows -> zeros
    unsigned lo = valid ? (unsigned)f2bf(tile[kp * 2][o])     : 0u;
    unsigned hi = valid ? (unsigned)f2bf(tile[kp * 2 + 1][o]) : 0u;
    *(unsigned*)(dst + (size_t)o * KDIM + kp * 2) = lo | (hi << 16);
  }
}

// ---------------- K3: grouped bf16 MFMA GEMM ----------------
// 128x128 tile, BK=64, XOR-swizzled LDS (0 bank conflicts), 2-slot dbuf,
// counted vmcnt(8) pipeline (never drains in loop), 4 phases/K-tile with
// setprio around MFMA clusters, subject->XCD block mapping.
__global__ __launch_bounds__(256, 2) void gemm_bf16(
    const unsigned short* __restrict__ xs,   // [8192][2048] bf16 (sorted)
    const unsigned short* __restrict__ Wt,   // [8][1024][2048] bf16
    const int* __restrict__ counts,
    const int* __restrict__ offsets,
    const int* __restrict__ perm,
    const float* __restrict__ bias,          // [8][1000]
    float* __restrict__ out)                 // [8192][1000]
{
  int b  = blockIdx.x;
  int s  = b & 7;                 // subject == XCD (hw round-robins bid%8)
  int r  = b >> 3;
  int nt = r & 7;
  int mt = r >> 3;                // 0..9
  int cnt = counts[s];
  int loc0 = mt * BM;
  if (loc0 >= cnt) return;
  int row0 = offsets[s] + loc0;
  int cnt_loc = cnt - loc0;

  __shared__ unsigned short lA[2][BM * BK];  // 2 x 16KB
  __shared__ unsigned short lB[2][BN * BK];  // 2 x 16KB
  __shared__ int permL[BM];

  int t = threadIdx.x;
  int lane = t & 63;
  int wave = t >> 6;

  // perm -> LDS, vmcnt-uniform across waves (all threads load; clamp index)
  {
    int pr = t & 127;
    int pidx = row0 + pr; if (pidx > NROWS - 1) pidx = NROWS - 1;
    permL[pr] = perm[pidx];       // validity decided later via (r < cnt_loc)
  }

  int wm = (wave >> 1) << 6;      // 2x2 waves, wave-tile 64x64
  int wn = (wave & 1) << 6;
  int frow = lane & 15, fk = lane >> 4;
  int axor = frow & 7;

  // staging geometry (R1-verified, 0 bank conflicts):
  // chunk cb covers rows cb*8..cb*8+7; phys k-chunk (lane&7) holds logical
  // chunk (lane&7)^(row&7)  -> read at phys (j ^ (row&7))
  int srck = (((lane & 7) ^ ((lane >> 3) & 7)) << 3);
  size_t gA[4], gB[4];
  unsigned lo[4];
  #pragma unroll
  for (int it = 0; it < 4; it++){
    int cb  = it * 4 + wave;               // 0..15
    int row = (cb << 3) + (lane >> 3);     // 0..127
    int ra  = row0 + row; if (ra > NROWS - 1) ra = NROWS - 1;
    gA[it] = (size_t)ra * KDIM + srck;
    gB[it] = ((size_t)(s * OPAD + nt * BN + row)) * KDIM + srck;
    lo[it] = (unsigned)((cb << 9) + (lane << 3));
  }

  f32x4 acc[4][4];
  #pragma unroll
  for (int i = 0; i < 4; i++)
    #pragma unroll
    for (int j = 0; j < 4; j++)
      #pragma unroll
      for (int e = 0; e < 4; e++) acc[i][j][e] = 0.f;

#define STAGE(slot, koff) do { \
    gload16(xs + gA[0] + (koff), (void*)(&lA[slot][lo[0]])); \
    gload16(xs + gA[1] + (koff), (void*)(&lA[slot][lo[1]])); \
    gload16(xs + gA[2] + (koff), (void*)(&lA[slot][lo[2]])); \
    gload16(xs + gA[3] + (koff), (void*)(&lA[slot][lo[3]])); \
    gload16(Wt + gB[0] + (koff), (void*)(&lB[slot][lo[0]])); \
    gload16(Wt + gB[1] + (koff), (void*)(&lB[slot][lo[1]])); \
    gload16(Wt + gB[2] + (koff), (void*)(&lB[slot][lo[2]])); \
    gload16(Wt + gB[3] + (koff), (void*)(&lB[slot][lo[3]])); \
  } while (0)

// tile-start: wait OLDEST 8 loads (this tile), leave next tile's 8 in flight
#define TSTART(n) do { \
    asm volatile("s_waitcnt vmcnt(" #n ")" ::: "memory"); \
    __builtin_amdgcn_sched_barrier(0); \
    __builtin_amdgcn_s_barrier(); \
    __builtin_amdgcn_sched_barrier(0); \
  } while (0)

// phase boundary: barrier first (hide ds latency under peer MFMA), then lgkm
#define PHASE_SYNC() do { \
    __builtin_amdgcn_s_barrier(); \
    asm volatile("s_waitcnt lgkmcnt(0)" ::: "memory"); \
    __builtin_amdgcn_sched_barrier(0); \
  } while (0)

#define AOFF(mi, ks) (((wm + ((mi) << 4) + frow) << 6) + ((((ks) * 4 + fk) ^ axor) << 3))
#define BOFF(ni, ks) (((wn + ((ni) << 4) + frow) << 6) + ((((ks) * 4 + fk) ^ axor) << 3))
#define LDA8(sl, mi, ks) (*(const short8v*)&lA[sl][AOFF(mi, ks)])
#define LDB8(sl, ni, ks) (*(const short8v*)&lB[sl][BOFF(ni, ks)])
#define MF(mi, ni, av, bv) acc[mi][ni] = __builtin_amdgcn_mfma_f32_16x16x32_bf16(av, bv, acc[mi][ni], 0, 0, 0)

#define TILE(sl) do { \
    short8v a0, a1, a2, a3, b0, b1, b2, b3; \
    /* ph0: ks0, ni 0-1 */ \
    a0 = LDA8(sl, 0, 0); a1 = LDA8(sl, 1, 0); a2 = LDA8(sl, 2, 0); a3 = LDA8(sl, 3, 0); \
    b0 = LDB8(sl, 0, 0); b1 = LDB8(sl, 1, 0); \
    PHASE_SYNC(); \
    __builtin_amdgcn_s_setprio(1); \
    MF(0, 0, a0, b0); MF(1, 0, a1, b0); MF(2, 0, a2, b0); MF(3, 0, a3, b0); \
    MF(0, 1, a0, b1); MF(1, 1, a1, b1); MF(2, 1, a2, b1); MF(3, 1, a3, b1); \
    __builtin_amdgcn_s_setprio(0); \
    /* ph1: ks0, ni 2-3 */ \
    b2 = LDB8(sl, 2, 0); b3 = LDB8(sl, 3, 0); \
    PHASE_SYNC(); \
    __builtin_amdgcn_s_setprio(1); \
    MF(0, 2, a0, b2); MF(1, 2, a1, b2); MF(2, 2, a2, b2); MF(3, 2, a3, b2); \
    MF(0, 3, a0, b3); MF(1, 3, a1, b3); MF(2, 3, a2, b3); MF(3, 3, a3, b3); \
    __builtin_amdgcn_s_setprio(0); \
    /* ph2: ks1, ni 0-1 */ \
    a0 = LDA8(sl, 0, 1); a1 = LDA8(sl, 1, 1); a2 = LDA8(sl, 2, 1); a3 = LDA8(sl, 3, 1); \
    b0 = LDB8(sl, 0, 1); b1 = LDB8(sl, 1, 1); \
    PHASE_SYNC(); \
    __builtin_amdgcn_s_setprio(1); \
    MF(0, 0, a0, b0); MF(1, 0, a1, b0); MF(2, 0, a2, b0); MF(3, 0, a3, b0); \
    MF(0, 1, a0, b1); MF(1, 1, a1, b1); MF(2, 1, a2, b1); MF(3, 1, a3, b1); \
    __builtin_amdgcn_s_setprio(0); \
    /* ph3: ks1, ni 2-3 */ \
    b2 = LDB8(sl, 2, 1); b3 = LDB8(sl, 3, 1); \
    PHASE_SYNC(); \
    __builtin_amdgcn_s_setprio(1); \
    MF(0, 2, a0, b2); MF(1, 2, a1, b2); MF(2, 2, a2, b2); MF(3, 2, a3, b2); \
    MF(0, 3, a0, b3); MF(1, 3, a1, b3); MF(2, 3, a2, b3); MF(3, 3, a3, b3); \
    __builtin_amdgcn_s_setprio(0); \
  } while (0)

  // prologue: 2 tiles in flight (perm load already drained by permL store)
  STAGE(0, 0);
  STAGE(1, BK);

  // main loop: tiles 0..29 (stage t+2 after tile t fully consumed)
  for (int it = 0; it < 15; ++it){
    int kb = it * 2 * BK;
    TSTART(8); TILE(0); STAGE(0, kb + 2 * BK);   // tile 2it,   stage 2it+2
    TSTART(8); TILE(1); STAGE(1, kb + 3 * BK);   // tile 2it+1, stage 2it+3
  }
  TSTART(8); TILE(0);                            // tile 30
  asm volatile("s_waitcnt vmcnt(0)" ::: "memory");
  __builtin_amdgcn_sched_barrier(0);
  __builtin_amdgcn_s_barrier();
  __builtin_amdgcn_sched_barrier(0);
  TILE(1);                                       // tile 31

  // epilogue: C/D layout col=lane&15, row=(lane>>4)*4+reg
  float bvn[4]; int ocol[4];
  #pragma unroll
  for (int ni = 0; ni < 4; ni++){
    int o = (nt << 7) + wn + (ni << 4) + frow;
    ocol[ni] = o;
    bvn[ni] = (o < ODIM) ? bias[s * ODIM + o] : 0.f;
  }
  #pragma unroll
  for (int mi = 0; mi < 4; mi++){
    int rbase = wm + (mi << 4) + (fk << 2);
    #pragma unroll
    for (int jj = 0; jj < 4; jj++){
      int rr = rbase + jj;
      if (rr < cnt_loc){
        int orow = permL[rr];
        #pragma unroll
        for (int ni = 0; ni < 4; ni++){
          if (ocol[ni] < ODIM)
            out[(size_t)orow * ODIM + ocol[ni]] = acc[mi][ni][jj] + bvn[ni];
        }
      }
    }
  }
#undef STAGE
#undef TSTART
#undef PHASE_SYNC
#undef AOFF
#undef BOFF
#undef LDA8
#undef LDB8
#undef MF
#undef TILE
}

// ---------------- fallback: naive fp32 (only if ws too small) ----------------
__global__ __launch_bounds__(256) void naive_kernel(const float* __restrict__ x,
                                                    const int* __restrict__ sid,
                                                    const float* __restrict__ W,
                                                    const float* __restrict__ bias,
                                                    float* __restrict__ out){
  __shared__ float xr[KDIM];
  int row = blockIdx.x;
  int s = sid[row];
  for (int i = threadIdx.x; i < KDIM; i += 256) xr[i] = x[(size_t)row * KDIM + i];
  __syncthreads();
  int o = blockIdx.y * 256 + threadIdx.x;
  if (o >= ODIM) return;
  const float* w = W + (size_t)s * KDIM * ODIM + o;
  float acc = bias[s * ODIM + o];
  for (int k = 0; k < KDIM; k++) acc = fmaf(xr[k], w[(size_t)k * ODIM], acc);
  out[(size_t)row * ODIM + o] = acc;
}

extern "C" void kernel_launch(void* const* d_in, const int* in_sizes, int n_in,
                              void* d_out, int out_size, void* d_ws, size_t ws_size,
                              hipStream_t stream) {
  const float* x    = (const float*)d_in[0];
  const int*   sid  = (const int*)d_in[1];
  const float* W    = (const float*)d_in[2];
  const float* bias = (const float*)d_in[3];
  float* out = (float*)d_out;

  const size_t XS_BYTES = (size_t)NROWS * KDIM * 2;
  const size_t WT_BYTES = (size_t)NSUB * OPAD * KDIM * 2;
  const size_t need = 64 + (size_t)NROWS * 4 + XS_BYTES + WT_BYTES;

  if (ws_size < need){
    naive_kernel<<<dim3(NROWS, 4), 256, 0, stream>>>(x, sid, W, bias, out);
    return;
  }

  char* w = (char*)d_ws;
  int* counts  = (int*)w;                      // 8 ints
  int* offsets = counts + 8;                   // 8 ints
  int* perm    = (int*)(w + 64);               // 8192 ints
  unsigned short* xs = (unsigned short*)(w + 64 + (size_t)NROWS * 4);
  unsigned short* Wt = xs + (size_t)NROWS * KDIM;

  build_perm <<<NSUB, 256, 0, stream>>>(sid, counts, offsets, perm);
  prep_fused <<<NROWS + 4096, 256, 0, stream>>>(x, perm, xs, W, Wt);
  gemm_bf16  <<<NSUB * 8 * MT_MAX, 256, 0, stream>>>(xs, Wt, counts, offsets, perm, bias, out);
}